// Round 6
// baseline (79.488 us; speedup 1.0000x reference)
//
#include <hip/hip_runtime.h>
#include <stdint.h>

// YOLOv3 head decode: B=32, NA=3 anchors, 76x76 grid, 85 attrs, stride=8.
// in : [B, 255, 76, 76] f32   (c-major, spatial contiguous)
// out: [B, 3*76*76, 85] f32   (attr contiguous)
//
// Per-block tile: one (b, anchor, gy) row = 85 channels x 76 floats = 1615 16B chunks.
//  phase 1: global -> LDS DMA (global_load_lds, 16B/lane), linear, zero VALU.
//  phase 2: lane m owns source chunk (cc=m%85, gxq=m/85):
//           ds_read_b128 at slot cc*19+gxq (lane stride 76 dwords == 12 mod 32
//           -> 8-lane bank windows tile all 32 banks: conflict-free),
//           transform (cc uniform per lane), 4 scalar NT stores at
//           out dword gxq*340 + 85t + cc (stride-1 across lanes: coalesced).

#define GH 76
#define GW 76
#define NA 3
#define ATTRS 85
#define SPATIAL (GH * GW)          // 5776
#define NCHUNK 1615                // 85 * 19
#define LOG2E 1.4426950408889634f

typedef float f32x4 __attribute__((ext_vector_type(4)));
typedef const __attribute__((address_space(1))) uint32_t gu32;
typedef __attribute__((address_space(3))) uint32_t lu32;

__global__ __launch_bounds__(512) void yolo_head_kernel(
    const float* __restrict__ in, float* __restrict__ out, int nwg) {
    // ---- bijective XCD swizzle (m204) ----
    const int L = blockIdx.x;
    const int q = nwg >> 3, r = nwg & 7, xcd = L & 7;
    const int W = (xcd < r ? xcd * (q + 1) : r * (q + 1) + (xcd - r) * q) + (L >> 3);
    const int gy = W % GH;
    const int a  = (W / GH) % NA;
    const int b  = W / (GH * NA);

    const float aw = (a == 0) ? 10.0f : (a == 1) ? 16.0f : 33.0f;
    const float ah = (a == 0) ? 13.0f : (a == 1) ? 30.0f : 23.0f;

    __shared__ float tile[NCHUNK * 4];   // 25840 B

    const float* inb = in + ((size_t)(b * (NA * ATTRS) + a * ATTRS)) * SPATIAL
                          + (size_t)gy * GW;
    const int tid = threadIdx.x;

    // ---- phase 1: DMA stage, source-coalesced (c slow, gcx fast), LDS linear ----
#pragma unroll
    for (int k = 0; k < 4; ++k) {
        const int s = tid + k * 512;
        if (s < NCHUNK) {
            const int c   = s / 19;        // channel (19-lane coalesced runs)
            const int gcx = s - c * 19;    // 16B chunk within row
            const float* src = inb + (size_t)c * SPATIAL + (gcx << 2);
            __builtin_amdgcn_global_load_lds((gu32*)src, (lu32*)&tile[s << 2], 16, 0, 0);
        }
    }
    __syncthreads();

    // ---- phase 2: transpose-read + transform + coalesced scalar NT stores ----
    float* outb = out + ((size_t)(b * NA + a) * SPATIAL + (size_t)gy * GW) * ATTRS;
#pragma unroll
    for (int k = 0; k < 4; ++k) {
        const int m = tid + k * 512;
        if (m < NCHUNK) {
            const int gxq = m / 85;            // 0..18
            const int cc  = m - gxq * 85;      // 0..84, consecutive across lanes
            const f32x4 v = *reinterpret_cast<const f32x4*>(&tile[(cc * 19 + gxq) << 2]);

            float E[4], res[4];
#pragma unroll
            for (int t = 0; t < 4; ++t) {
                E[t]   = __builtin_amdgcn_exp2f(LOG2E * v[t]);          // e^x
                res[t] = E[t] * __builtin_amdgcn_rcpf(1.0f + E[t]);     // sigmoid
            }
            if (cc < 4) {                       // ~3 lanes/wave, uniform per lane
                const float gx0 = (float)(gxq << 2);
#pragma unroll
                for (int t = 0; t < 4; ++t) {
                    if      (cc == 0) res[t] = (res[t] + gx0 + (float)t) * 8.0f;
                    else if (cc == 1) res[t] = (res[t] + (float)gy) * 8.0f;
                    else if (cc == 2) res[t] = E[t] * aw;
                    else              res[t] = E[t] * ah;
                }
            }
            float* po = outb + gxq * 340 + cc;  // lane-stride 1 dword: coalesced
#pragma unroll
            for (int t = 0; t < 4; ++t)
                __builtin_nontemporal_store(res[t], po + 85 * t);
        }
    }
}

extern "C" void kernel_launch(void* const* d_in, const int* in_sizes, int n_in,
                              void* d_out, int out_size, void* d_ws, size_t ws_size,
                              hipStream_t stream) {
    const float* in = (const float*)d_in[0];
    float* out = (float*)d_out;
    const int B = in_sizes[0] / (NA * ATTRS * SPATIAL);  // 32
    const int nwg = GH * NA * B;                         // 7296
    yolo_head_kernel<<<dim3(nwg), 512, 0, stream>>>(in, out, nwg);
}

// Round 7
// 60.824 us; speedup vs baseline: 1.3068x; 1.3068x over previous
//
#include <hip/hip_runtime.h>
#include <stdint.h>

// YOLOv3 head decode: B=32, NA=3 anchors, 76x76 grid, 85 attrs, stride=8.
// in : [B, 255, 76, 76] f32   (c-major, spatial contiguous)
// out: [B, 3*76*76, 85] f32   (attr contiguous)
//
// Per-block tile: one (b, anchor, gy) row = 85 channels x 76 floats.
//  phase 1 : global -> LDS DMA (global_load_lds 16B), linear [cc][gxq], 0 VALU.
//  phase 2a: lane m -> chunk (cc=m%85, gxq=m/85): ds_read_b128 at slot
//            cc*19+gxq (stride 76 dw == 12 mod 32: banks tile conflict-free),
//            transform in regs (channel uniform per lane).
//  phase 2b: scatter ds_write_b32 to [gx][c] at (gxq*4+t)*85+cc --
//            consecutive addresses across lanes: conflict-free.
//  phase 3 : contiguous ds_read_b128 + contiguous NT dwordx4 stores
//            (exactly the R5 store stream: WRITE_SIZE = 187 MB flat).

#define GH 76
#define GW 76
#define NA 3
#define ATTRS 85
#define SPATIAL (GH * GW)          // 5776
#define NCHUNK 1615                // 85 * 19 = 76*85/4
#define LOG2E 1.4426950408889634f

typedef float f32x4 __attribute__((ext_vector_type(4)));
typedef const __attribute__((address_space(1))) uint32_t gu32;
typedef __attribute__((address_space(3))) uint32_t lu32;

__global__ __launch_bounds__(512) void yolo_head_kernel(
    const float* __restrict__ in, float* __restrict__ out, int nwg) {
    // ---- bijective XCD swizzle (m204) ----
    const int L = blockIdx.x;
    const int q = nwg >> 3, r = nwg & 7, xcd = L & 7;
    const int W = (xcd < r ? xcd * (q + 1) : r * (q + 1) + (xcd - r) * q) + (L >> 3);
    const int gy = W % GH;
    const int a  = (W / GH) % NA;
    const int b  = W / (GH * NA);

    const float aw = (a == 0) ? 10.0f : (a == 1) ? 16.0f : 33.0f;
    const float ah = (a == 0) ? 13.0f : (a == 1) ? 30.0f : 23.0f;

    __shared__ float tile[NCHUNK * 4];   // 25840 B, reused for both layouts

    const float* inb = in + ((size_t)(b * (NA * ATTRS) + a * ATTRS)) * SPATIAL
                          + (size_t)gy * GW;
    const int tid = threadIdx.x;

    // ---- phase 1: DMA stage, source-coalesced, LDS linear [cc][gxq] ----
#pragma unroll
    for (int k = 0; k < 4; ++k) {
        const int s = tid + k * 512;
        if (s < NCHUNK) {
            const int c   = s / 19;
            const int gcx = s - c * 19;
            const float* src = inb + (size_t)c * SPATIAL + (gcx << 2);
            __builtin_amdgcn_global_load_lds((gu32*)src, (lu32*)&tile[s << 2], 16, 0, 0);
        }
    }
    __syncthreads();

    // ---- phase 2a: conflict-free transpose-read + transform (registers) ----
    f32x4 res[4];
    int gxq_[4], cc_[4];
#pragma unroll
    for (int k = 0; k < 4; ++k) {
        const int m = tid + k * 512;
        if (m < NCHUNK) {
            const int gxq = m / 85;            // 0..18
            const int cc  = m - gxq * 85;      // consecutive across lanes
            gxq_[k] = gxq; cc_[k] = cc;
            const f32x4 v = *reinterpret_cast<const f32x4*>(&tile[(cc * 19 + gxq) << 2]);
            f32x4 E, rs;
#pragma unroll
            for (int t = 0; t < 4; ++t) {
                E[t]  = __builtin_amdgcn_exp2f(LOG2E * v[t]);        // e^x
                rs[t] = E[t] * __builtin_amdgcn_rcpf(1.0f + E[t]);   // sigmoid
            }
            if (cc < 4) {                       // ~4/85 lanes, short body
                const float gx0 = (float)(gxq << 2);
#pragma unroll
                for (int t = 0; t < 4; ++t) {
                    if      (cc == 0) rs[t] = (rs[t] + gx0 + (float)t) * 8.0f;
                    else if (cc == 1) rs[t] = (rs[t] + (float)gy) * 8.0f;
                    else if (cc == 2) rs[t] = E[t] * aw;
                    else              rs[t] = E[t] * ah;
                }
            }
            res[k] = rs;
        }
    }
    __syncthreads();   // all reads of staged layout done

    // ---- phase 2b: scatter to [gx][c]; consecutive lane addresses: conflict-free ----
#pragma unroll
    for (int k = 0; k < 4; ++k) {
        const int m = tid + k * 512;
        if (m < NCHUNK) {
            const int base = (gxq_[k] << 2) * ATTRS + cc_[k];
#pragma unroll
            for (int t = 0; t < 4; ++t)
                tile[base + t * ATTRS] = res[k][t];
        }
    }
    __syncthreads();

    // ---- phase 3: contiguous LDS read + contiguous NT dwordx4 store ----
    float* outb = out + ((size_t)(b * NA + a) * SPATIAL + (size_t)gy * GW) * ATTRS;
#pragma unroll
    for (int k = 0; k < 4; ++k) {
        const int m = tid + k * 512;
        if (m < NCHUNK) {
            const f32x4 v = *reinterpret_cast<const f32x4*>(&tile[m << 2]);
            __builtin_nontemporal_store(v, reinterpret_cast<f32x4*>(outb + (m << 2)));
        }
    }
}

extern "C" void kernel_launch(void* const* d_in, const int* in_sizes, int n_in,
                              void* d_out, int out_size, void* d_ws, size_t ws_size,
                              hipStream_t stream) {
    const float* in = (const float*)d_in[0];
    float* out = (float*)d_out;
    const int B = in_sizes[0] / (NA * ATTRS * SPATIAL);  // 32
    const int nwg = GH * NA * B;                         // 7296
    yolo_head_kernel<<<dim3(nwg), 512, 0, stream>>>(in, out, nwg);
}